// Round 7
// baseline (273.848 us; speedup 1.0000x reference)
//
#include <hip/hip_runtime.h>
#include <hip/hip_bf16.h>

typedef __attribute__((ext_vector_type(8))) short short8;
typedef __attribute__((ext_vector_type(4))) float float4v;
typedef __attribute__((ext_vector_type(4))) unsigned int uint4v;
typedef __attribute__((ext_vector_type(2))) unsigned int uint2v;

#define SS 8192
#define EE 512
#define NKB 16
#define AP 520    // A row pitch in shorts (1040 B, 16B-aligned; bank step 4 -> reads 2-way (free))

__device__ __forceinline__ unsigned int f2bf1(float f) {
    unsigned int u = __builtin_bit_cast(unsigned int, f);
    return (u + 0x7fffu + ((u >> 16) & 1u)) >> 16;   // RNE, inputs finite
}
__device__ __forceinline__ unsigned int pack2(float lo, float hi) {
    return f2bf1(lo) | (f2bf1(hi) << 16);
}

// ---------- prep: W fp32 [512][512] -> bf16 ws [kb][n][32] (linear) ----------
__global__ void w_prep(const float* __restrict__ W, unsigned short* __restrict__ Wws) {
    int idx = blockIdx.x * 256 + threadIdx.x;        // 65536 threads x 4 elems
    int n  = idx >> 7;                               // W row (= output col) 0..511
    int kg = idx & 127;
    int k  = kg * 4;
    float4v v = *(const float4v*)(W + (size_t)n * EE + k);
    int kb = k >> 5, kl = k & 31;
    unsigned short* dst = Wws + ((size_t)kb * (EE * 32) + (size_t)n * 32 + kl);
    uint2v pk = { pack2(v.x, v.y), pack2(v.z, v.w) };
    *(uint2v*)dst = pk;
}

// ---------- main v8: M=32 head-split tile, 4 blocks/CU, barrier-free K-loop ----------
// Block = (b, sc, mh): heads [mh*32,+32) x all 512 out-cols. M-split splits x
// column-wise (head h reads x cols h*8..+8) -> zero duplicate HBM traffic.
// A[32][512] bf16 in LDS (33.3 KB) staged once; W streams global->VGPR
// single-buffered (8 frags); ONE barrier total; TLP (4 waves/SIMD) hides latency.
__global__ __launch_bounds__(256, 4)
void qmha_fused8(const float* __restrict__ x, const float* __restrict__ theta,
                 const unsigned short* __restrict__ Wws, float* __restrict__ out)
{
    __shared__ __attribute__((aligned(16))) unsigned short A_lds[32 * AP];  // 33280 B

    const int bx = blockIdx.x;                       // 2048 blocks
    const int mh = bx & 1;
    const int sc = (bx >> 1) & 127;
    const int b  = bx >> 8;
    const int t = threadIdx.x, lane = t & 63, wid = t >> 6;   // wid 0..3
    const int fr = lane & 15, q = lane >> 4;

    // b-frag global base: wave wid owns W rows [wid*128, +128); frag nt at +nt*512
    const unsigned short* wbase = Wws + ((size_t)(wid * 128 + fr) * 32 + q * 8);

    // prefetch kb=0 b-frags (lands under the staging phase)
    short8 bA[8];
    #pragma unroll
    for (int nt = 0; nt < 8; ++nt)
        bA[nt] = *(const short8*)(wbase + nt * 512);

    const float th0 = theta[0], th1 = theta[1], th2 = theta[2], th3 = theta[3];
    const float th4 = theta[4], th5 = theta[5], th6 = theta[6], th7 = theta[7];

    // ---- A staging: A[m][s_loc*8+j] = cos(x[b, sc*64+s_loc, (mh*32+m)*8+j] + theta[j]) ----
    // thread t: m = t&31, covers s_loc = (t>>5)*8 + it (it 0..7). Half-wave reads 1KB contig.
    {
        const int m = t & 31, g = t >> 5;
        const float* xs = x + ((size_t)b * SS + (size_t)sc * 64 + (size_t)g * 8) * EE
                          + mh * 256 + m * 8;
        unsigned short* aw = A_lds + m * AP + g * 64;
        #pragma unroll
        for (int it = 0; it < 8; ++it) {
            const float* px = xs + (size_t)it * EE;
            float4v v0 = *(const float4v*)(px);
            float4v v1 = *(const float4v*)(px + 4);
            float c0 = __cosf(v0.x + th0), c1 = __cosf(v0.y + th1);
            float c2 = __cosf(v0.z + th2), c3 = __cosf(v0.w + th3);
            float c4 = __cosf(v1.x + th4), c5 = __cosf(v1.y + th5);
            float c6 = __cosf(v1.z + th6), c7 = __cosf(v1.w + th7);
            uint4v pk = { pack2(c0,c1), pack2(c2,c3), pack2(c4,c5), pack2(c6,c7) };
            *(uint4v*)(aw + it * 8) = pk;
        }
    }

    __syncthreads();   // the only block-wide sync

    float4v acc[2][8];
    #pragma unroll
    for (int i = 0; i < 2; ++i)
        #pragma unroll
        for (int j = 0; j < 8; ++j)
            acc[i][j] = (float4v){0.f, 0.f, 0.f, 0.f};

    const int aoff = fr * AP + q * 8;                // + mt*16*AP + kb*32

    // ---- K-loop: barrier-free, single-buffered b, tail prefetch, counted waits ----
    #pragma unroll
    for (int kb = 0; kb < NKB; ++kb) {
        short8 af0 = *(const short8*)&A_lds[aoff + kb * 32];
        short8 af1 = *(const short8*)&A_lds[aoff + 16 * AP + kb * 32];
        __builtin_amdgcn_s_setprio(1);
        #pragma unroll
        for (int nt = 0; nt < 8; ++nt) {
            acc[0][nt] = __builtin_amdgcn_mfma_f32_16x16x32_bf16(af0, bA[nt], acc[0][nt], 0, 0, 0);
            acc[1][nt] = __builtin_amdgcn_mfma_f32_16x16x32_bf16(af1, bA[nt], acc[1][nt], 0, 0, 0);
        }
        __builtin_amdgcn_s_setprio(0);
        if (kb < NKB - 1) {                          // refill bA for kb+1 (reads-in-order WAR-safe)
            const unsigned short* wn = wbase + (size_t)(kb + 1) * (EE * 32);
            #pragma unroll
            for (int nt = 0; nt < 8; ++nt)
                bA[nt] = *(const short8*)(wn + nt * 512);
        }
    }

    // ---- epilogue: C/D col=lane&15, row=(lane>>4)*4+reg (validated mapping) ----
    // out view-row = (mh*32 + mt*16 + q*4 + r)*128 + sc ; col n = wid*128 + nt*16 + fr
    float* outb = out + (size_t)b * (SS * EE)
                  + ((size_t)mh * 4096 + sc) * EE + wid * 128 + fr;
    #pragma unroll
    for (int mt = 0; mt < 2; ++mt) {
        #pragma unroll
        for (int r = 0; r < 4; ++r) {
            const int mloc = mt * 16 + q * 4 + r;
            float* po = outb + (size_t)mloc * (128 * EE);
            #pragma unroll
            for (int nt = 0; nt < 8; ++nt)
                po[nt * 16] = acc[mt][nt][r];
        }
    }
}

// ---------- fallback (round-1 kernel, used only if ws too small) ----------
#define AS 520
#define WSF 40
#define HH 64
__global__ __launch_bounds__(256, 2)
void qmha_fused_fb(const float* __restrict__ x, const float* __restrict__ theta,
                   const float* __restrict__ W, float* __restrict__ out)
{
    __shared__ __attribute__((aligned(16))) unsigned short A_lds[HH * AS];
    __shared__ __attribute__((aligned(16))) unsigned short W_lds[128 * WSF];
    const int bx = blockIdx.x;
    const int ntile = (bx >> 3) & 3;
    const int p = ((bx >> 5) << 3) | (bx & 7);
    const int b = p >> 7;
    const int sc = p & 127;
    const int t = threadIdx.x, lane = t & 63, wid = t >> 6;
    const int wn = t >> 1, wk = (t & 1) * 16;
    const float* Wbase = W + (size_t)(ntile * 128 + wn) * EE + wk;
    float4v wv0 = *(const float4v*)(Wbase + 0);
    float4v wv1 = *(const float4v*)(Wbase + 4);
    float4v wv2 = *(const float4v*)(Wbase + 8);
    float4v wv3 = *(const float4v*)(Wbase + 12);
    const float th0 = theta[0], th1 = theta[1], th2 = theta[2], th3 = theta[3];
    const float th4 = theta[4], th5 = theta[5], th6 = theta[6], th7 = theta[7];
    {
        const float* xb = x + ((size_t)b * SS + (size_t)sc * 64) * EE + lane * 8;
        #pragma unroll
        for (int it = 0; it < 16; ++it) {
            const int s_loc = wid * 16 + it;
            const float* px = xb + (size_t)s_loc * EE;
            float4v v0 = *(const float4v*)(px);
            float4v v1 = *(const float4v*)(px + 4);
            float c0 = __cosf(v0.x + th0), c1 = __cosf(v0.y + th1);
            float c2 = __cosf(v0.z + th2), c3 = __cosf(v0.w + th3);
            float c4 = __cosf(v1.x + th4), c5 = __cosf(v1.y + th5);
            float c6 = __cosf(v1.z + th6), c7 = __cosf(v1.w + th7);
            uint4v pk = { pack2(c0,c1), pack2(c2,c3), pack2(c4,c5), pack2(c6,c7) };
            *(uint4v*)&A_lds[lane * AS + s_loc * 8] = pk;
        }
    }
    float4v acc[2][4];
    #pragma unroll
    for (int i = 0; i < 2; ++i)
        #pragma unroll
        for (int j = 0; j < 4; ++j)
            acc[i][j] = (float4v){0.f, 0.f, 0.f, 0.f};
    const int m0 = (wid >> 1) * 32, n0l = (wid & 1) * 64;
    const int fr = lane & 15, q = lane >> 4;
    const unsigned short* Arow0 = &A_lds[(m0 + fr) * AS + q * 8];
    const unsigned short* Arow1 = Arow0 + 16 * AS;
    const unsigned short* Wrow  = &W_lds[(n0l + fr) * WSF + q * 8];
    for (int kb = 0; kb < NKB; ++kb) {
        __syncthreads();
        {
            uint4v lo = { pack2(wv0.x, wv0.y), pack2(wv0.z, wv0.w),
                          pack2(wv1.x, wv1.y), pack2(wv1.z, wv1.w) };
            uint4v hi = { pack2(wv2.x, wv2.y), pack2(wv2.z, wv2.w),
                          pack2(wv3.x, wv3.y), pack2(wv3.z, wv3.w) };
            *(uint4v*)&W_lds[wn * WSF + wk]     = lo;
            *(uint4v*)&W_lds[wn * WSF + wk + 8] = hi;
        }
        if (kb < NKB - 1) {
            const float* Wn = Wbase + (size_t)(kb + 1) * 32;
            wv0 = *(const float4v*)(Wn + 0);
            wv1 = *(const float4v*)(Wn + 4);
            wv2 = *(const float4v*)(Wn + 8);
            wv3 = *(const float4v*)(Wn + 12);
        }
        __syncthreads();
        short8 a0 = *(const short8*)(Arow0 + kb * 32);
        short8 a1 = *(const short8*)(Arow1 + kb * 32);
        short8 b0 = *(const short8*)(Wrow + 0 * 16 * WSF);
        short8 b1 = *(const short8*)(Wrow + 1 * 16 * WSF);
        short8 b2 = *(const short8*)(Wrow + 2 * 16 * WSF);
        short8 b3 = *(const short8*)(Wrow + 3 * 16 * WSF);
        acc[0][0] = __builtin_amdgcn_mfma_f32_16x16x32_bf16(a0, b0, acc[0][0], 0, 0, 0);
        acc[0][1] = __builtin_amdgcn_mfma_f32_16x16x32_bf16(a0, b1, acc[0][1], 0, 0, 0);
        acc[0][2] = __builtin_amdgcn_mfma_f32_16x16x32_bf16(a0, b2, acc[0][2], 0, 0, 0);
        acc[0][3] = __builtin_amdgcn_mfma_f32_16x16x32_bf16(a0, b3, acc[0][3], 0, 0, 0);
        acc[1][0] = __builtin_amdgcn_mfma_f32_16x16x32_bf16(a1, b0, acc[1][0], 0, 0, 0);
        acc[1][1] = __builtin_amdgcn_mfma_f32_16x16x32_bf16(a1, b1, acc[1][1], 0, 0, 0);
        acc[1][2] = __builtin_amdgcn_mfma_f32_16x16x32_bf16(a1, b2, acc[1][2], 0, 0, 0);
        acc[1][3] = __builtin_amdgcn_mfma_f32_16x16x32_bf16(a1, b3, acc[1][3], 0, 0, 0);
    }
    const int colbase = ntile * 128 + n0l + fr;
    #pragma unroll
    for (int mt = 0; mt < 2; ++mt) {
        #pragma unroll
        for (int r = 0; r < 4; ++r) {
            const int hrow = m0 + mt * 16 + q * 4 + r;
            float* po = out + ((size_t)b * SS + (size_t)hrow * 128 + sc) * EE + colbase;
            po[0 * 16] = acc[mt][0][r];
            po[1 * 16] = acc[mt][1][r];
            po[2 * 16] = acc[mt][2][r];
            po[3 * 16] = acc[mt][3][r];
        }
    }
}

extern "C" void kernel_launch(void* const* d_in, const int* in_sizes, int n_in,
                              void* d_out, int out_size, void* d_ws, size_t ws_size,
                              hipStream_t stream) {
    const float* x     = (const float*)d_in[0];
    const float* theta = (const float*)d_in[1];
    const float* W     = (const float*)d_in[2];
    float* out         = (float*)d_out;

    if (ws_size >= (size_t)EE * EE * sizeof(unsigned short)) {
        unsigned short* Wws = (unsigned short*)d_ws;
        w_prep<<<dim3(256), dim3(256), 0, stream>>>(W, Wws);
        qmha_fused8<<<dim3(2048), dim3(256), 0, stream>>>(x, theta, Wws, out);
    } else {
        qmha_fused_fb<<<dim3(4096), dim3(256), 0, stream>>>(x, theta, W, out);
    }
}